// Round 8
// baseline (1864.342 us; speedup 1.0000x reference)
//
#include <hip/hip_runtime.h>
#include <stdint.h>
#include <math.h>

#define N_ROWS 8192
#define N_TOK  8192
#define N_DIM  512
#define N_SAMP 10
#define GK     1536   // 3 * 512, bf16x2 split zones

typedef __attribute__((ext_vector_type(8))) short bf16x8_t;
typedef __attribute__((ext_vector_type(4))) float f32x4_t;

// ---------------- JAX threefry2x32 (exact) ----------------
__host__ __device__ __forceinline__ void tf2x32(uint32_t ks0, uint32_t ks1,
                                                uint32_t& x0, uint32_t& x1) {
  uint32_t ks2 = ks0 ^ ks1 ^ 0x1BD11BDAu;
  x0 += ks0; x1 += ks1;
#define TF_ROUND(r) { x0 += x1; x1 = (x1 << (r)) | (x1 >> (32 - (r))); x1 ^= x0; }
  TF_ROUND(13) TF_ROUND(15) TF_ROUND(26) TF_ROUND(6)
  x0 += ks1; x1 += ks2 + 1u;
  TF_ROUND(17) TF_ROUND(29) TF_ROUND(16) TF_ROUND(24)
  x0 += ks2; x1 += ks0 + 2u;
  TF_ROUND(13) TF_ROUND(15) TF_ROUND(26) TF_ROUND(6)
  x0 += ks0; x1 += ks1 + 3u;
  TF_ROUND(17) TF_ROUND(29) TF_ROUND(16) TF_ROUND(24)
  x0 += ks1; x1 += ks2 + 4u;
  TF_ROUND(13) TF_ROUND(15) TF_ROUND(26) TF_ROUND(6)
  x0 += ks2; x1 += ks0 + 5u;
#undef TF_ROUND
}

__device__ __forceinline__ unsigned short f2bf_rne(float f) {
  uint32_t u = __float_as_uint(f);
  uint32_t r = (u + 0x7fffu + ((u >> 16) & 1u)) >> 16;
  return (unsigned short)r;
}
__device__ __forceinline__ float bf2f(unsigned short h) {
  return __uint_as_float((uint32_t)h << 16);
}

// ---------------- row sum-of-squares ----------------
__global__ __launch_bounds__(256) void rownorm_kernel(const float* __restrict__ M,
                                                      float* __restrict__ out) {
  int lane = threadIdx.x & 63;
  int row = (int)((blockIdx.x * blockDim.x + threadIdx.x) >> 6);
  const float* p = M + (size_t)row * N_DIM;
  float acc = 0.f;
#pragma unroll
  for (int d = 0; d < N_DIM; d += 64) {
    float v = p[d + lane];
    acc = fmaf(v, v, acc);
  }
#pragma unroll
  for (int off = 32; off; off >>= 1) acc += __shfl_xor(acc, off, 64);
  if (lane == 0) out[row] = acc;
}

__global__ __launch_bounds__(256) void init_state_kernel(float* __restrict__ rmin,
                                                         int* __restrict__ ridx) {
  int i = blockIdx.x * 256 + threadIdx.x;
  if (i < N_ROWS * N_SAMP) { rmin[i] = INFINITY; ridx[i] = 0; }
}

// ---------------- bf16x2 split ----------------
__global__ __launch_bounds__(256) void split_kernel(const float* __restrict__ src,
                                                    unsigned short* __restrict__ dst,
                                                    int mode) {
  int t = blockIdx.x * 256 + threadIdx.x;
  int row = t >> 7;
  int c = (t & 127) << 2;
  float4 v = *(const float4*)(src + (size_t)row * N_DIM + c);
  ushort4 hi, lo;
  hi.x = f2bf_rne(v.x); lo.x = f2bf_rne(v.x - bf2f(hi.x));
  hi.y = f2bf_rne(v.y); lo.y = f2bf_rne(v.y - bf2f(hi.y));
  hi.z = f2bf_rne(v.z); lo.z = f2bf_rne(v.z - bf2f(hi.z));
  hi.w = f2bf_rne(v.w); lo.w = f2bf_rne(v.w - bf2f(hi.w));
  unsigned short* base = dst + (size_t)row * GK;
  *(ushort4*)(base + c) = hi;
  if (mode == 0) {
    *(ushort4*)(base + 512 + c) = lo;
    *(ushort4*)(base + 1024 + c) = hi;
  } else {
    *(ushort4*)(base + 512 + c) = hi;
    *(ushort4*)(base + 1024 + c) = lo;
  }
}

// ---------------- bf16 MFMA NT GEMM, async staging + XOR bank swizzle, E-epilogue ----------------
// LDS slot c (16B) holds (row = c>>2, kchunk = (c&3) ^ ((c>>3)&3)).
// Read side: (row, quad) lives at slot 4*row + (quad ^ ((row>>1)&3)); within a
// 16-lane read phase this spreads lanes 2-per-bank-group (2-way = free, m136)
// instead of 8-per-group (~2.9x stall).
__device__ __forceinline__ void async_cp16(const void* g, void* l) {
  __builtin_amdgcn_global_load_lds((const __attribute__((address_space(1))) void*)g,
                                   (__attribute__((address_space(3))) void*)l, 16, 0, 0);
}

__global__ __launch_bounds__(256) void gemm_bf16_kernel(const unsigned short* __restrict__ A2,
                                                        const unsigned short* __restrict__ B2,
                                                        const float* __restrict__ xx,
                                                        const float* __restrict__ ee,
                                                        float* __restrict__ E,
                                                        int ks, int KC) {
  __shared__ __align__(16) unsigned short As[128 * 32];
  __shared__ __align__(16) unsigned short Bs[128 * 32];
  int tid = threadIdx.x;
  int w = tid >> 6, l = tid & 63;
  int row0 = blockIdx.y * 128;
  int col0 = blockIdx.x * 128;
  int bcol0 = ks + col0;
  int wm = (w & 1) * 64, wn = (w >> 1) * 64;
  int quad = l >> 4, r15 = l & 15;

  f32x4_t acc[4][4];
#pragma unroll
  for (int i = 0; i < 4; ++i)
#pragma unroll
    for (int j = 0; j < 4; ++j) acc[i][j] = (f32x4_t){0.f, 0.f, 0.f, 0.f};

  int c0 = w * 64 + l;
  int c1 = c0 + 256;
  int q0 = (c0 & 3) ^ ((c0 >> 3) & 3);   // swizzled global k-chunk for slot c0
  int q1 = (c1 & 3) ^ ((c1 >> 3) & 3);
  const size_t ga0 = (size_t)(row0 + (c0 >> 2)) * GK + q0 * 8;
  const size_t ga1 = (size_t)(row0 + (c1 >> 2)) * GK + q1 * 8;
  const size_t gb0 = (size_t)(bcol0 + (c0 >> 2)) * GK + q0 * 8;
  const size_t gb1 = (size_t)(bcol0 + (c1 >> 2)) * GK + q1 * 8;

  int sw = (r15 >> 1) & 3;               // read-side swizzle (== (row>>1)&3, rows offset by mult of 16)
  int qa = (quad ^ sw) * 8;

  for (int k0 = 0; k0 < GK; k0 += 32) {
    async_cp16(A2 + ga0 + k0, As + c0 * 8);
    async_cp16(A2 + ga1 + k0, As + c1 * 8);
    async_cp16(B2 + gb0 + k0, Bs + c0 * 8);
    async_cp16(B2 + gb1 + k0, Bs + c1 * 8);
    __syncthreads();

    bf16x8_t af[4], bf[4];
#pragma unroll
    for (int i = 0; i < 4; ++i)
      af[i] = *(const bf16x8_t*)&As[(wm + i * 16 + r15) * 32 + qa];
#pragma unroll
    for (int j = 0; j < 4; ++j)
      bf[j] = *(const bf16x8_t*)&Bs[(wn + j * 16 + r15) * 32 + qa];
#pragma unroll
    for (int i = 0; i < 4; ++i)
#pragma unroll
      for (int j = 0; j < 4; ++j)
        acc[i][j] = __builtin_amdgcn_mfma_f32_16x16x32_bf16(af[i], bf[j], acc[i][j], 0, 0, 0);
    __syncthreads();
  }

  // epilogue: C/D layout col=lane&15, row=(lane>>4)*4+reg; E = expf(dist)
  const float inv_nt = 1.f / 8192.f;
  float eev[4];
#pragma unroll
  for (int j = 0; j < 4; ++j) eev[j] = ee[ks + col0 + wn + j * 16 + r15];
#pragma unroll
  for (int i = 0; i < 4; ++i) {
#pragma unroll
    for (int r = 0; r < 4; ++r) {
      int grow = row0 + wm + i * 16 + quad * 4 + r;
      float xxv = xx[grow];
#pragma unroll
      for (int j = 0; j < 4; ++j) {
        int gcol = col0 + wn + j * 16 + r15;
        float dist = (xxv + eev[j] - 2.0f * acc[i][j][r]) * inv_nt;
        E[(size_t)grow * KC + gcol] = expf(dist);
      }
    }
  }
}

// ---------------- fp32 NT GEMM (fallback) with E-epilogue ----------------
__global__ __launch_bounds__(256) void gemm_nt_kernel(const float* __restrict__ A,
                                                      const float* __restrict__ B,
                                                      const float* __restrict__ xx,
                                                      const float* __restrict__ ee,
                                                      float* __restrict__ E,
                                                      int ks, int KC) {
  __shared__ __align__(16) float Asf[32][68];
  __shared__ __align__(16) float Bsf[32][68];
  int tid = threadIdx.x;
  int row0 = blockIdx.y * 64;
  int colB0 = blockIdx.x * 64 + ks;
  int tx = tid & 15, ty = tid >> 4;
  float acc[4][4] = {};
  for (int d0 = 0; d0 < N_DIM; d0 += 32) {
#pragma unroll
    for (int r = 0; r < 2; ++r) {
      int c = tid + 256 * r;
      int m = c >> 3;
      int dv = (c & 7) << 2;
      const float4 va = *(const float4*)(A + (size_t)(row0 + m) * N_DIM + d0 + dv);
      Asf[dv + 0][m] = va.x; Asf[dv + 1][m] = va.y;
      Asf[dv + 2][m] = va.z; Asf[dv + 3][m] = va.w;
      const float4 vb = *(const float4*)(B + (size_t)(colB0 + m) * N_DIM + d0 + dv);
      Bsf[dv + 0][m] = vb.x; Bsf[dv + 1][m] = vb.y;
      Bsf[dv + 2][m] = vb.z; Bsf[dv + 3][m] = vb.w;
    }
    __syncthreads();
#pragma unroll
    for (int dd = 0; dd < 32; ++dd) {
      float4 a4 = *(const float4*)&Asf[dd][ty << 2];
      float4 b4 = *(const float4*)&Bsf[dd][tx << 2];
      float av[4] = {a4.x, a4.y, a4.z, a4.w};
      float bv[4] = {b4.x, b4.y, b4.z, b4.w};
#pragma unroll
      for (int i = 0; i < 4; ++i)
#pragma unroll
        for (int j = 0; j < 4; ++j)
          acc[i][j] = fmaf(av[i], bv[j], acc[i][j]);
    }
    __syncthreads();
  }
  const float inv_nt = 1.f / 8192.f;
  int colC0 = blockIdx.x * 64;
  float eev[4];
#pragma unroll
  for (int j = 0; j < 4; ++j) eev[j] = ee[ks + colC0 + (tx << 2) + j];
#pragma unroll
  for (int i = 0; i < 4; ++i) {
    int grow = row0 + (ty << 2) + i;
    float xxv = xx[grow];
    float4 v;
    v.x = expf((xxv + eev[0] - 2.0f * acc[i][0]) * inv_nt);
    v.y = expf((xxv + eev[1] - 2.0f * acc[i][1]) * inv_nt);
    v.z = expf((xxv + eev[2] - 2.0f * acc[i][2]) * inv_nt);
    v.w = expf((xxv + eev[3] - 2.0f * acc[i][3]) * inv_nt);
    *(float4*)(E + (size_t)grow * KC + colC0 + (tx << 2)) = v;
  }
}

// ---------------- gumbel argmin sampler with bits-domain screening ----------------
// wv = (-logf(u))*E, min over k. Screen: dist >= 0 -> E > 1, so -log(u) >= bmin
// guarantees wv > bmin. u = (bits>>9)*2^-23 EXACTLY, monotone in bits, so the
// screen is one uint compare per draw; slow path is the exact r6 arithmetic.
__global__ __launch_bounds__(256) void sample_kernel(const float* __restrict__ E,
                                                     float* __restrict__ rmin,
                                                     int* __restrict__ ridx,
                                                     int ks, int KC,
                                                     uint32_t k0, uint32_t k1) {
  int lane = threadIdx.x & 63;
  int row = (int)((blockIdx.x * blockDim.x + threadIdx.x) >> 6);
  float bmin[N_SAMP];
  int bidx[N_SAMP];
  uint32_t th[N_SAMP];   // skip iff bits < th[s]
#pragma unroll
  for (int s = 0; s < N_SAMP; ++s) { bmin[s] = INFINITY; bidx[s] = 0; th[s] = 0u; }
  const float tiny = 1.1754943508222875e-38f;
  uint32_t row_c = (uint32_t)row * 81920u;

  for (int kk = lane; kk < KC; kk += 64) {
    int k = ks + kk;
    float Ek = E[(size_t)row * KC + kk];
    uint32_t base_c = row_c + (uint32_t)k;
#pragma unroll
    for (int s = 0; s < N_SAMP; ++s) {
      uint32_t x0 = 0u, x1 = base_c + (uint32_t)s * 8192u;
      tf2x32(k0, k1, x0, x1);
      uint32_t bits = x0 ^ x1;
      if (bits >= th[s]) {                    // possible winner (rare after warm-up)
        float u = __uint_as_float(0x3f800000u | (bits >> 9)) - 1.0f;
        u = fmaxf(u, tiny);
        float wv = -logf(u) * Ek;             // exact r6 arithmetic
        if (wv < bmin[s]) {
          bmin[s] = wv; bidx[s] = k;
          float ut = expf(-wv) * 0.999999f;   // conservative margin; underflow->0 => th=0 (no skip)
          th[s] = ((uint32_t)(ut * 8388608.0f)) << 9;
        }
      }
    }
  }
  // wave arg-reduce: min value, ties -> smallest index
#pragma unroll
  for (int s = 0; s < N_SAMP; ++s) {
    float v = bmin[s];
    int id = bidx[s];
#pragma unroll
    for (int off = 32; off; off >>= 1) {
      float ov = __shfl_xor(v, off, 64);
      int oi = __shfl_xor(id, off, 64);
      if (ov < v || (ov == v && oi < id)) { v = ov; id = oi; }
    }
    if (lane == 0) {
      size_t p = (size_t)row * N_SAMP + s;
      if (v < rmin[p]) { rmin[p] = v; ridx[p] = id; }
    }
  }
}

// ---------------- gather + mean + straight-through ----------------
__global__ __launch_bounds__(256) void gather_kernel(const float* __restrict__ emb,
                                                     const int* __restrict__ ridx,
                                                     const float* __restrict__ x,
                                                     float* __restrict__ outq,
                                                     float* __restrict__ outs) {
  int lane = threadIdx.x & 63;
  int row = (int)((blockIdx.x * blockDim.x + threadIdx.x) >> 6);
  int idx[N_SAMP];
#pragma unroll
  for (int s = 0; s < N_SAMP; ++s) idx[s] = ridx[row * N_SAMP + s];
  if (lane < N_SAMP) outs[row * N_SAMP + lane] = (float)idx[lane];
#pragma unroll
  for (int c = lane; c < N_DIM; c += 64) {
    float sum = 0.f;
#pragma unroll
    for (int s = 0; s < N_SAMP; ++s) sum += emb[(size_t)idx[s] * N_DIM + c];
    float qe = sum / 10.0f;
    float xv = x[(size_t)row * N_DIM + c];
    outq[(size_t)row * N_DIM + c] = xv + (qe - xv);
  }
}

extern "C" void kernel_launch(void* const* d_in, const int* in_sizes, int n_in,
                              void* d_out, int out_size, void* d_ws, size_t ws_size,
                              hipStream_t stream) {
  const float* x = (const float*)d_in[0];
  const float* emb = (const float*)d_in[1];
  float* out_q = (float*)d_out;
  float* out_s = out_q + (size_t)N_ROWS * N_DIM;

  const size_t fixed_f = (size_t)N_ROWS + N_TOK + 2 * (size_t)N_ROWS * N_SAMP;  // 180224 floats
  const size_t out_f = (size_t)N_ROWS * N_DIM + (size_t)N_ROWS * N_SAMP;
  const size_t split_u = (size_t)N_ROWS * GK;

  uint32_t s0 = 0u, s1 = 1u;   // skey = fold_in(key(0), 1)
  tf2x32(0u, 0u, s0, s1);

  // ---- preferred path: bf16x2 MFMA GEMM, fixed + 2 splits + E strip in ws ----
  int KC = 0;
  for (int c = 8192; c >= 128; c >>= 1) {
    size_t need = fixed_f * 4 + 2 * split_u * 2 + (size_t)N_ROWS * c * 4;
    if (need <= ws_size) { KC = c; break; }
  }

  if (KC) {
    float* xx = (float*)d_ws;
    float* ee = xx + N_ROWS;
    float* rmin = ee + N_TOK;
    int* ridx = (int*)(rmin + (size_t)N_ROWS * N_SAMP);
    unsigned short* A2 = (unsigned short*)(ridx + (size_t)N_ROWS * N_SAMP);
    unsigned short* B2 = A2 + split_u;
    float* E = (float*)(B2 + split_u);

    rownorm_kernel<<<2048, 256, 0, stream>>>(x, xx);
    rownorm_kernel<<<2048, 256, 0, stream>>>(emb, ee);
    init_state_kernel<<<(N_ROWS * N_SAMP + 255) / 256, 256, 0, stream>>>(rmin, ridx);
    split_kernel<<<N_ROWS * 128 / 256, 256, 0, stream>>>(x, A2, 0);
    split_kernel<<<N_ROWS * 128 / 256, 256, 0, stream>>>(emb, B2, 1);

    for (int ks = 0; ks < N_TOK; ks += KC) {
      gemm_bf16_kernel<<<dim3(KC / 128, N_ROWS / 128), 256, 0, stream>>>(A2, B2, xx, ee, E, ks, KC);
      sample_kernel<<<2048, 256, 0, stream>>>(E, rmin, ridx, ks, KC, s0, s1);
    }
    gather_kernel<<<2048, 256, 0, stream>>>(emb, ridx, x, out_q, out_s);
    return;
  }

  // ---- fallback: fp32 path with adaptive placement ----
  float *xx, *ee, *rmin, *E;
  int* ridx;
  KC = 0;
  for (int c = 8192; c >= 64; c >>= 1) {
    if ((fixed_f + (size_t)N_ROWS * c) * 4 <= ws_size) { KC = c; break; }
  }
  if (KC) {
    xx = (float*)d_ws;
    ee = xx + N_ROWS;
    rmin = ee + N_TOK;
    ridx = (int*)(rmin + (size_t)N_ROWS * N_SAMP);
    E = (float*)(ridx + (size_t)N_ROWS * N_SAMP);
  } else if (fixed_f * 4 <= ws_size) {
    KC = 512;
    xx = (float*)d_ws;
    ee = xx + N_ROWS;
    rmin = ee + N_TOK;
    ridx = (int*)(rmin + (size_t)N_ROWS * N_SAMP);
    E = out_q;
  } else {
    KC = 256;
    E = out_q;
    float* tail = out_q + (out_f - fixed_f);
    xx = tail;
    ee = xx + N_ROWS;
    rmin = ee + N_TOK;
    ridx = (int*)(rmin + (size_t)N_ROWS * N_SAMP);
  }

  rownorm_kernel<<<2048, 256, 0, stream>>>(x, xx);
  rownorm_kernel<<<2048, 256, 0, stream>>>(emb, ee);
  init_state_kernel<<<(N_ROWS * N_SAMP + 255) / 256, 256, 0, stream>>>(rmin, ridx);
  for (int ks = 0; ks < N_TOK; ks += KC) {
    gemm_nt_kernel<<<dim3(KC / 64, N_ROWS / 64), 256, 0, stream>>>(x, emb, xx, ee, E, ks, KC);
    sample_kernel<<<2048, 256, 0, stream>>>(E, rmin, ridx, ks, KC, s0, s1);
  }
  gather_kernel<<<2048, 256, 0, stream>>>(emb, ridx, x, out_q, out_s);
}

// Round 9
// 1701.860 us; speedup vs baseline: 1.0955x; 1.0955x over previous
//
#include <hip/hip_runtime.h>
#include <stdint.h>
#include <math.h>

#define N_ROWS 8192
#define N_TOK  8192
#define N_DIM  512
#define N_SAMP 10
#define GK     1536   // 3 * 512, bf16x2 split zones

typedef __attribute__((ext_vector_type(8))) short bf16x8_t;
typedef __attribute__((ext_vector_type(4))) float f32x4_t;

// ---------------- JAX threefry2x32 (exact) ----------------
__host__ __device__ __forceinline__ void tf2x32(uint32_t ks0, uint32_t ks1,
                                                uint32_t& x0, uint32_t& x1) {
  uint32_t ks2 = ks0 ^ ks1 ^ 0x1BD11BDAu;
  x0 += ks0; x1 += ks1;
#define TF_ROUND(r) { x0 += x1; x1 = (x1 << (r)) | (x1 >> (32 - (r))); x1 ^= x0; }
  TF_ROUND(13) TF_ROUND(15) TF_ROUND(26) TF_ROUND(6)
  x0 += ks1; x1 += ks2 + 1u;
  TF_ROUND(17) TF_ROUND(29) TF_ROUND(16) TF_ROUND(24)
  x0 += ks2; x1 += ks0 + 2u;
  TF_ROUND(13) TF_ROUND(15) TF_ROUND(26) TF_ROUND(6)
  x0 += ks0; x1 += ks1 + 3u;
  TF_ROUND(17) TF_ROUND(29) TF_ROUND(16) TF_ROUND(24)
  x0 += ks1; x1 += ks2 + 4u;
  TF_ROUND(13) TF_ROUND(15) TF_ROUND(26) TF_ROUND(6)
  x0 += ks2; x1 += ks0 + 5u;
#undef TF_ROUND
}

__device__ __forceinline__ unsigned short f2bf_rne(float f) {
  uint32_t u = __float_as_uint(f);
  uint32_t r = (u + 0x7fffu + ((u >> 16) & 1u)) >> 16;
  return (unsigned short)r;
}
__device__ __forceinline__ float bf2f(unsigned short h) {
  return __uint_as_float((uint32_t)h << 16);
}

__device__ __forceinline__ unsigned long long shfl_xor_u64(unsigned long long v, int off) {
  uint32_t lo = (uint32_t)v, hi = (uint32_t)(v >> 32);
  lo = (uint32_t)__shfl_xor((int)lo, off, 64);
  hi = (uint32_t)__shfl_xor((int)hi, off, 64);
  return ((unsigned long long)hi << 32) | lo;
}

// ---------------- row sum-of-squares ----------------
__global__ __launch_bounds__(256) void rownorm_kernel(const float* __restrict__ M,
                                                      float* __restrict__ out) {
  int lane = threadIdx.x & 63;
  int row = (int)((blockIdx.x * blockDim.x + threadIdx.x) >> 6);
  const float* p = M + (size_t)row * N_DIM;
  float acc = 0.f;
#pragma unroll
  for (int d = 0; d < N_DIM; d += 64) {
    float v = p[d + lane];
    acc = fmaf(v, v, acc);
  }
#pragma unroll
  for (int off = 32; off; off >>= 1) acc += __shfl_xor(acc, off, 64);
  if (lane == 0) out[row] = acc;
}

__global__ __launch_bounds__(256) void init_state_kernel(float* __restrict__ rmin,
                                                         int* __restrict__ ridx) {
  int i = blockIdx.x * 256 + threadIdx.x;
  if (i < N_ROWS * N_SAMP) { rmin[i] = INFINITY; ridx[i] = 0; }
}

// ---------------- bf16x2 split ----------------
__global__ __launch_bounds__(256) void split_kernel(const float* __restrict__ src,
                                                    unsigned short* __restrict__ dst,
                                                    int mode) {
  int t = blockIdx.x * 256 + threadIdx.x;
  int row = t >> 7;
  int c = (t & 127) << 2;
  float4 v = *(const float4*)(src + (size_t)row * N_DIM + c);
  ushort4 hi, lo;
  hi.x = f2bf_rne(v.x); lo.x = f2bf_rne(v.x - bf2f(hi.x));
  hi.y = f2bf_rne(v.y); lo.y = f2bf_rne(v.y - bf2f(hi.y));
  hi.z = f2bf_rne(v.z); lo.z = f2bf_rne(v.z - bf2f(hi.z));
  hi.w = f2bf_rne(v.w); lo.w = f2bf_rne(v.w - bf2f(hi.w));
  unsigned short* base = dst + (size_t)row * GK;
  *(ushort4*)(base + c) = hi;
  if (mode == 0) {
    *(ushort4*)(base + 512 + c) = lo;
    *(ushort4*)(base + 1024 + c) = hi;
  } else {
    *(ushort4*)(base + 512 + c) = hi;
    *(ushort4*)(base + 1024 + c) = lo;
  }
}

// ---------------- bf16 MFMA NT GEMM, BK=64, banded swizzle, E-epilogue ----------------
// Same MFMA k-order as the r6 BK=32 kernel -> E bit-identical.
__device__ __forceinline__ void async_cp16(const void* g, void* l) {
  __builtin_amdgcn_global_load_lds((const __attribute__((address_space(1))) void*)g,
                                   (__attribute__((address_space(3))) void*)l, 16, 0, 0);
}

__global__ __launch_bounds__(256) void gemm_bf16_kernel(const unsigned short* __restrict__ A2,
                                                        const unsigned short* __restrict__ B2,
                                                        const float* __restrict__ xx,
                                                        const float* __restrict__ ee,
                                                        float* __restrict__ E,
                                                        int ks, int KC) {
  __shared__ __align__(16) unsigned short As[128 * 64];
  __shared__ __align__(16) unsigned short Bs[128 * 64];
  int tid = threadIdx.x;
  int w = tid >> 6, l = tid & 63;

  // banded swizzle: 64 consecutive bids cover an 8x8 supertile (A 8 tiles + B 8
  // tiles ~ 6 MB hot set) instead of 1 row x 64 cols (25 MB B per row-band).
  int gx = gridDim.x;
  int bid = blockIdx.y * gx + blockIdx.x;
  int band = bid / (8 * gx);
  int t8 = bid % (8 * gx);
  int by = band * 8 + (t8 & 7);
  int bx = t8 >> 3;

  int row0 = by * 128;
  int col0 = bx * 128;
  int bcol0 = ks + col0;
  int wm = (w & 1) * 64, wn = (w >> 1) * 64;
  int quad = l >> 4, r15 = l & 15;

  f32x4_t acc[4][4];
#pragma unroll
  for (int i = 0; i < 4; ++i)
#pragma unroll
    for (int j = 0; j < 4; ++j) acc[i][j] = (f32x4_t){0.f, 0.f, 0.f, 0.f};

  // 128x64 bf16 tile = 1024 x 16B chunks; thread stages chunks tid + 256*r.
  // chunk c: row = c>>3, kchunk = c&7. LDS dest = c*16B (lane-contiguous).
  for (int k0 = 0; k0 < GK; k0 += 64) {
#pragma unroll
    for (int r = 0; r < 4; ++r) {
      int c = tid + 256 * r;
      int rw = c >> 3, kc = c & 7;
      async_cp16(A2 + (size_t)(row0 + rw) * GK + k0 + kc * 8, As + c * 8);
      async_cp16(B2 + (size_t)(bcol0 + rw) * GK + k0 + kc * 8, Bs + c * 8);
    }
    __syncthreads();

#pragma unroll
    for (int kk2 = 0; kk2 < 2; ++kk2) {
      bf16x8_t af[4], bf[4];
#pragma unroll
      for (int i = 0; i < 4; ++i)
        af[i] = *(const bf16x8_t*)&As[(wm + i * 16 + r15) * 64 + kk2 * 32 + quad * 8];
#pragma unroll
      for (int j = 0; j < 4; ++j)
        bf[j] = *(const bf16x8_t*)&Bs[(wn + j * 16 + r15) * 64 + kk2 * 32 + quad * 8];
#pragma unroll
      for (int i = 0; i < 4; ++i)
#pragma unroll
        for (int j = 0; j < 4; ++j)
          acc[i][j] = __builtin_amdgcn_mfma_f32_16x16x32_bf16(af[i], bf[j], acc[i][j], 0, 0, 0);
    }
    __syncthreads();
  }

  // epilogue: C/D layout col=lane&15, row=(lane>>4)*4+reg; E = expf(dist)
  const float inv_nt = 1.f / 8192.f;
  float eev[4];
#pragma unroll
  for (int j = 0; j < 4; ++j) eev[j] = ee[ks + col0 + wn + j * 16 + r15];
#pragma unroll
  for (int i = 0; i < 4; ++i) {
#pragma unroll
    for (int r = 0; r < 4; ++r) {
      int grow = row0 + wm + i * 16 + quad * 4 + r;
      float xxv = xx[grow];
#pragma unroll
      for (int j = 0; j < 4; ++j) {
        int gcol = col0 + wn + j * 16 + r15;
        float dist = (xxv + eev[j] - 2.0f * acc[i][j][r]) * inv_nt;
        E[(size_t)grow * KC + gcol] = expf(dist);
      }
    }
  }
}

// ---------------- fp32 NT GEMM (fallback, r6-proven) with E-epilogue ----------------
__global__ __launch_bounds__(256) void gemm_nt_kernel(const float* __restrict__ A,
                                                      const float* __restrict__ B,
                                                      const float* __restrict__ xx,
                                                      const float* __restrict__ ee,
                                                      float* __restrict__ E,
                                                      int ks, int KC) {
  __shared__ __align__(16) float Asf[32][68];
  __shared__ __align__(16) float Bsf[32][68];
  int tid = threadIdx.x;
  int row0 = blockIdx.y * 64;
  int colB0 = blockIdx.x * 64 + ks;
  int tx = tid & 15, ty = tid >> 4;
  float acc[4][4] = {};
  for (int d0 = 0; d0 < N_DIM; d0 += 32) {
#pragma unroll
    for (int r = 0; r < 2; ++r) {
      int c = tid + 256 * r;
      int m = c >> 3;
      int dv = (c & 7) << 2;
      const float4 va = *(const float4*)(A + (size_t)(row0 + m) * N_DIM + d0 + dv);
      Asf[dv + 0][m] = va.x; Asf[dv + 1][m] = va.y;
      Asf[dv + 2][m] = va.z; Asf[dv + 3][m] = va.w;
      const float4 vb = *(const float4*)(B + (size_t)(colB0 + m) * N_DIM + d0 + dv);
      Bsf[dv + 0][m] = vb.x; Bsf[dv + 1][m] = vb.y;
      Bsf[dv + 2][m] = vb.z; Bsf[dv + 3][m] = vb.w;
    }
    __syncthreads();
#pragma unroll
    for (int dd = 0; dd < 32; ++dd) {
      float4 a4 = *(const float4*)&Asf[dd][ty << 2];
      float4 b4 = *(const float4*)&Bsf[dd][tx << 2];
      float av[4] = {a4.x, a4.y, a4.z, a4.w};
      float bv[4] = {b4.x, b4.y, b4.z, b4.w};
#pragma unroll
      for (int i = 0; i < 4; ++i)
#pragma unroll
        for (int j = 0; j < 4; ++j)
          acc[i][j] = fmaf(av[i], bv[j], acc[i][j]);
    }
    __syncthreads();
  }
  const float inv_nt = 1.f / 8192.f;
  int colC0 = blockIdx.x * 64;
  float eev[4];
#pragma unroll
  for (int j = 0; j < 4; ++j) eev[j] = ee[ks + colC0 + (tx << 2) + j];
#pragma unroll
  for (int i = 0; i < 4; ++i) {
    int grow = row0 + (ty << 2) + i;
    float xxv = xx[grow];
    float4 v;
    v.x = expf((xxv + eev[0] - 2.0f * acc[i][0]) * inv_nt);
    v.y = expf((xxv + eev[1] - 2.0f * acc[i][1]) * inv_nt);
    v.z = expf((xxv + eev[2] - 2.0f * acc[i][2]) * inv_nt);
    v.w = expf((xxv + eev[3] - 2.0f * acc[i][3]) * inv_nt);
    *(float4*)(E + (size_t)grow * KC + colC0 + (tx << 2)) = v;
  }
}

// ---------------- sampler: wave-shared champion + bits-domain screen ----------------
// wv = (-logf(u))*E, min over k (== r6). Skip a draw iff bits < th[s], where th
// guarantees -log(u) > champ_wv; since E > 1 strictly, such draws cannot beat the
// champion. Slow body is wave-uniform (__any) and updates a wave-shared packed
// champion (wv_bits<<32|k): identical winner + tie rule as r6's exhaustive scan.
__global__ __launch_bounds__(256) void sample_kernel(const float* __restrict__ E,
                                                     float* __restrict__ rmin,
                                                     int* __restrict__ ridx,
                                                     int ks, int KC,
                                                     uint32_t k0, uint32_t k1) {
  int lane = threadIdx.x & 63;
  int row = (int)((blockIdx.x * blockDim.x + threadIdx.x) >> 6);
  unsigned long long champ[N_SAMP];
  uint32_t th[N_SAMP];
#pragma unroll
  for (int s = 0; s < N_SAMP; ++s) { champ[s] = 0xFFFFFFFFFFFFFFFFULL; th[s] = 0u; }
  const float tiny = 1.1754943508222875e-38f;
  uint32_t row_c = (uint32_t)row * 81920u;

  for (int kk = lane; kk < KC; kk += 64) {
    uint32_t k = (uint32_t)(ks + kk);
    float Ek = E[(size_t)row * KC + kk];
    uint32_t base_c = row_c + k;
#pragma unroll
    for (int s = 0; s < N_SAMP; ++s) {
      uint32_t x0 = 0u, x1 = base_c + (uint32_t)s * 8192u;
      tf2x32(k0, k1, x0, x1);
      uint32_t bits = x0 ^ x1;
      bool cand = (bits >= th[s]);
      if (__any(cand)) {
        float u = __uint_as_float(0x3f800000u | (bits >> 9)) - 1.0f;
        u = fmaxf(u, tiny);
        float wv = -logf(u) * Ek;             // exact r6 arithmetic
        unsigned long long p = cand
            ? (((unsigned long long)__float_as_uint(wv) << 32) | k)
            : 0xFFFFFFFFFFFFFFFFULL;
#pragma unroll
        for (int off = 1; off < 64; off <<= 1) {
          unsigned long long op = shfl_xor_u64(p, off);
          p = (op < p) ? op : p;
        }
        if (p < champ[s]) {
          champ[s] = p;
          float wmin = __uint_as_float((uint32_t)(p >> 32));
          float ut = expf(-wmin) * 0.999999f;  // conservative; underflow->0 => no skip
          th[s] = ((uint32_t)(ut * 8388608.0f)) << 9;
        }
      }
    }
  }
#pragma unroll
  for (int s = 0; s < N_SAMP; ++s) {
    if (lane == 0) {
      float v = __uint_as_float((uint32_t)(champ[s] >> 32));
      int id = (int)(uint32_t)(champ[s] & 0xFFFFFFFFu);
      size_t p = (size_t)row * N_SAMP + s;
      if (v < rmin[p]) { rmin[p] = v; ridx[p] = id; }
    }
  }
}

// ---------------- gather + mean + straight-through (float4) ----------------
__global__ __launch_bounds__(256) void gather_kernel(const float* __restrict__ emb,
                                                     const int* __restrict__ ridx,
                                                     const float* __restrict__ x,
                                                     float* __restrict__ outq,
                                                     float* __restrict__ outs) {
  int lane = threadIdx.x & 63;
  int row = (int)((blockIdx.x * blockDim.x + threadIdx.x) >> 6);
  int idx[N_SAMP];
#pragma unroll
  for (int s = 0; s < N_SAMP; ++s) idx[s] = ridx[row * N_SAMP + s];
  if (lane < N_SAMP) outs[row * N_SAMP + lane] = (float)idx[lane];
#pragma unroll
  for (int h = 0; h < 2; ++h) {
    int c = h * 256 + lane * 4;
    float4 sum = make_float4(0.f, 0.f, 0.f, 0.f);
#pragma unroll
    for (int s = 0; s < N_SAMP; ++s) {
      float4 e = *(const float4*)(emb + (size_t)idx[s] * N_DIM + c);
      sum.x += e.x; sum.y += e.y; sum.z += e.z; sum.w += e.w;
    }
    float4 xv = *(const float4*)(x + (size_t)row * N_DIM + c);
    float4 o;
    o.x = xv.x + (sum.x / 10.0f - xv.x);
    o.y = xv.y + (sum.y / 10.0f - xv.y);
    o.z = xv.z + (sum.z / 10.0f - xv.z);
    o.w = xv.w + (sum.w / 10.0f - xv.w);
    *(float4*)(outq + (size_t)row * N_DIM + c) = o;
  }
}

extern "C" void kernel_launch(void* const* d_in, const int* in_sizes, int n_in,
                              void* d_out, int out_size, void* d_ws, size_t ws_size,
                              hipStream_t stream) {
  const float* x = (const float*)d_in[0];
  const float* emb = (const float*)d_in[1];
  float* out_q = (float*)d_out;
  float* out_s = out_q + (size_t)N_ROWS * N_DIM;

  const size_t fixed_f = (size_t)N_ROWS + N_TOK + 2 * (size_t)N_ROWS * N_SAMP;  // 180224 floats
  const size_t out_f = (size_t)N_ROWS * N_DIM + (size_t)N_ROWS * N_SAMP;
  const size_t split_u = (size_t)N_ROWS * GK;

  uint32_t s0 = 0u, s1 = 1u;   // skey = fold_in(key(0), 1)
  tf2x32(0u, 0u, s0, s1);

  // ---- preferred path: bf16x2 MFMA GEMM, fixed + 2 splits + E strip in ws ----
  int KC = 0;
  for (int c = 8192; c >= 128; c >>= 1) {
    size_t need = fixed_f * 4 + 2 * split_u * 2 + (size_t)N_ROWS * c * 4;
    if (need <= ws_size) { KC = c; break; }
  }

  if (KC) {
    float* xx = (float*)d_ws;
    float* ee = xx + N_ROWS;
    float* rmin = ee + N_TOK;
    int* ridx = (int*)(rmin + (size_t)N_ROWS * N_SAMP);
    unsigned short* A2 = (unsigned short*)(ridx + (size_t)N_ROWS * N_SAMP);
    unsigned short* B2 = A2 + split_u;
    float* E = (float*)(B2 + split_u);

    rownorm_kernel<<<2048, 256, 0, stream>>>(x, xx);
    rownorm_kernel<<<2048, 256, 0, stream>>>(emb, ee);
    init_state_kernel<<<(N_ROWS * N_SAMP + 255) / 256, 256, 0, stream>>>(rmin, ridx);
    split_kernel<<<N_ROWS * 128 / 256, 256, 0, stream>>>(x, A2, 0);
    split_kernel<<<N_ROWS * 128 / 256, 256, 0, stream>>>(emb, B2, 1);

    for (int ks = 0; ks < N_TOK; ks += KC) {
      gemm_bf16_kernel<<<dim3(KC / 128, N_ROWS / 128), 256, 0, stream>>>(A2, B2, xx, ee, E, ks, KC);
      sample_kernel<<<2048, 256, 0, stream>>>(E, rmin, ridx, ks, KC, s0, s1);
    }
    gather_kernel<<<2048, 256, 0, stream>>>(emb, ridx, x, out_q, out_s);
    return;
  }

  // ---- fallback: fp32 path with adaptive placement ----
  float *xx, *ee, *rmin, *E;
  int* ridx;
  KC = 0;
  for (int c = 8192; c >= 64; c >>= 1) {
    if ((fixed_f + (size_t)N_ROWS * c) * 4 <= ws_size) { KC = c; break; }
  }
  if (KC) {
    xx = (float*)d_ws;
    ee = xx + N_ROWS;
    rmin = ee + N_TOK;
    ridx = (int*)(rmin + (size_t)N_ROWS * N_SAMP);
    E = (float*)(ridx + (size_t)N_ROWS * N_SAMP);
  } else if (fixed_f * 4 <= ws_size) {
    KC = 512;
    xx = (float*)d_ws;
    ee = xx + N_ROWS;
    rmin = ee + N_TOK;
    ridx = (int*)(rmin + (size_t)N_ROWS * N_SAMP);
    E = out_q;
  } else {
    KC = 256;
    E = out_q;
    float* tail = out_q + (out_f - fixed_f);
    xx = tail;
    ee = xx + N_ROWS;
    rmin = ee + N_TOK;
    ridx = (int*)(rmin + (size_t)N_ROWS * N_SAMP);
  }

  rownorm_kernel<<<2048, 256, 0, stream>>>(x, xx);
  rownorm_kernel<<<2048, 256, 0, stream>>>(emb, ee);
  init_state_kernel<<<(N_ROWS * N_SAMP + 255) / 256, 256, 0, stream>>>(rmin, ridx);
  for (int ks = 0; ks < N_TOK; ks += KC) {
    gemm_nt_kernel<<<dim3(KC / 64, N_ROWS / 64), 256, 0, stream>>>(x, emb, xx, ee, E, ks, KC);
    sample_kernel<<<2048, 256, 0, stream>>>(E, rmin, ridx, ks, KC, s0, s1);
  }
  gather_kernel<<<2048, 256, 0, stream>>>(emb, ridx, x, out_q, out_s);
}

// Round 10
// 1628.677 us; speedup vs baseline: 1.1447x; 1.0449x over previous
//
#include <hip/hip_runtime.h>
#include <stdint.h>
#include <math.h>

#define N_ROWS 8192
#define N_TOK  8192
#define N_DIM  512
#define N_SAMP 10
#define GK     1536   // 3 * 512, bf16x2 split zones

typedef __attribute__((ext_vector_type(8))) short bf16x8_t;
typedef __attribute__((ext_vector_type(4))) float f32x4_t;

// ---------------- JAX threefry2x32 (exact) ----------------
__host__ __device__ __forceinline__ void tf2x32(uint32_t ks0, uint32_t ks1,
                                                uint32_t& x0, uint32_t& x1) {
  uint32_t ks2 = ks0 ^ ks1 ^ 0x1BD11BDAu;
  x0 += ks0; x1 += ks1;
#define TF_ROUND(r) { x0 += x1; x1 = (x1 << (r)) | (x1 >> (32 - (r))); x1 ^= x0; }
  TF_ROUND(13) TF_ROUND(15) TF_ROUND(26) TF_ROUND(6)
  x0 += ks1; x1 += ks2 + 1u;
  TF_ROUND(17) TF_ROUND(29) TF_ROUND(16) TF_ROUND(24)
  x0 += ks2; x1 += ks0 + 2u;
  TF_ROUND(13) TF_ROUND(15) TF_ROUND(26) TF_ROUND(6)
  x0 += ks0; x1 += ks1 + 3u;
  TF_ROUND(17) TF_ROUND(29) TF_ROUND(16) TF_ROUND(24)
  x0 += ks1; x1 += ks2 + 4u;
  TF_ROUND(13) TF_ROUND(15) TF_ROUND(26) TF_ROUND(6)
  x0 += ks2; x1 += ks0 + 5u;
#undef TF_ROUND
}

__device__ __forceinline__ unsigned short f2bf_rne(float f) {
  uint32_t u = __float_as_uint(f);
  uint32_t r = (u + 0x7fffu + ((u >> 16) & 1u)) >> 16;
  return (unsigned short)r;
}
__device__ __forceinline__ float bf2f(unsigned short h) {
  return __uint_as_float((uint32_t)h << 16);
}

__device__ __forceinline__ unsigned long long shfl_xor_u64(unsigned long long v, int off) {
  uint32_t lo = (uint32_t)v, hi = (uint32_t)(v >> 32);
  lo = (uint32_t)__shfl_xor((int)lo, off, 64);
  hi = (uint32_t)__shfl_xor((int)hi, off, 64);
  return ((unsigned long long)hi << 32) | lo;
}

// ---------------- row sum-of-squares ----------------
__global__ __launch_bounds__(256) void rownorm_kernel(const float* __restrict__ M,
                                                      float* __restrict__ out) {
  int lane = threadIdx.x & 63;
  int row = (int)((blockIdx.x * blockDim.x + threadIdx.x) >> 6);
  const float* p = M + (size_t)row * N_DIM;
  float acc = 0.f;
#pragma unroll
  for (int d = 0; d < N_DIM; d += 64) {
    float v = p[d + lane];
    acc = fmaf(v, v, acc);
  }
#pragma unroll
  for (int off = 32; off; off >>= 1) acc += __shfl_xor(acc, off, 64);
  if (lane == 0) out[row] = acc;
}

__global__ __launch_bounds__(256) void init_state_kernel(float* __restrict__ rmin,
                                                         int* __restrict__ ridx) {
  int i = blockIdx.x * 256 + threadIdx.x;
  if (i < N_ROWS * N_SAMP) { rmin[i] = INFINITY; ridx[i] = 0; }
}

// ---------------- bf16x2 split ----------------
__global__ __launch_bounds__(256) void split_kernel(const float* __restrict__ src,
                                                    unsigned short* __restrict__ dst,
                                                    int mode) {
  int t = blockIdx.x * 256 + threadIdx.x;
  int row = t >> 7;
  int c = (t & 127) << 2;
  float4 v = *(const float4*)(src + (size_t)row * N_DIM + c);
  ushort4 hi, lo;
  hi.x = f2bf_rne(v.x); lo.x = f2bf_rne(v.x - bf2f(hi.x));
  hi.y = f2bf_rne(v.y); lo.y = f2bf_rne(v.y - bf2f(hi.y));
  hi.z = f2bf_rne(v.z); lo.z = f2bf_rne(v.z - bf2f(hi.z));
  hi.w = f2bf_rne(v.w); lo.w = f2bf_rne(v.w - bf2f(hi.w));
  unsigned short* base = dst + (size_t)row * GK;
  *(ushort4*)(base + c) = hi;
  if (mode == 0) {
    *(ushort4*)(base + 512 + c) = lo;
    *(ushort4*)(base + 1024 + c) = hi;
  } else {
    *(ushort4*)(base + 512 + c) = hi;
    *(ushort4*)(base + 1024 + c) = lo;
  }
}

// ---------------- bf16 MFMA NT GEMM, BK=64, XOR bank swizzle, E-epilogue ----------------
// LDS slot(row, kc) = row*8 + (kc ^ (row&7)), 16B chunks. Read-side banks become
// ((kk2*4+quad)^(r15&7))*4 -> all 32 banks, 8 word-accesses each = b128 floor
// (was: bank = f(quad) only -> 16-way aliasing on half the banks). Staging keeps
// wave-uniform-base + lane*16 LDS dests and 128B-contiguous global reads.
// Fragment contents (and thus MFMA order and E) bit-identical to r6/r9.
__device__ __forceinline__ void async_cp16(const void* g, void* l) {
  __builtin_amdgcn_global_load_lds((const __attribute__((address_space(1))) void*)g,
                                   (__attribute__((address_space(3))) void*)l, 16, 0, 0);
}

__global__ __launch_bounds__(256) void gemm_bf16_kernel(const unsigned short* __restrict__ A2,
                                                        const unsigned short* __restrict__ B2,
                                                        const float* __restrict__ xx,
                                                        const float* __restrict__ ee,
                                                        float* __restrict__ E,
                                                        int ks, int KC) {
  __shared__ __align__(16) unsigned short As[128 * 64];
  __shared__ __align__(16) unsigned short Bs[128 * 64];
  int tid = threadIdx.x;
  int w = tid >> 6, l = tid & 63;

  // banded swizzle: 64 consecutive bids cover an 8x8 supertile (~6 MB hot set).
  int gx = gridDim.x;
  int bid = blockIdx.y * gx + blockIdx.x;
  int band = bid / (8 * gx);
  int t8 = bid % (8 * gx);
  int by = band * 8 + (t8 & 7);
  int bx = t8 >> 3;

  int row0 = by * 128;
  int col0 = bx * 128;
  int bcol0 = ks + col0;
  int wm = (w & 1) * 64, wn = (w >> 1) * 64;
  int quad = l >> 4, r15 = l & 15;

  f32x4_t acc[4][4];
#pragma unroll
  for (int i = 0; i < 4; ++i)
#pragma unroll
    for (int j = 0; j < 4; ++j) acc[i][j] = (f32x4_t){0.f, 0.f, 0.f, 0.f};

  // 128x64 tile = 1024 slots; thread stages slots c = tid + 256*r.
  // slot c: row = c>>3, holds global kchunk (c&7)^(row&7); LDS dest = c*16B.
  int srow[4], skc[4];
#pragma unroll
  for (int r = 0; r < 4; ++r) {
    int c = tid + 256 * r;
    srow[r] = c >> 3;
    skc[r] = (c & 7) ^ (srow[r] & 7);
  }

  for (int k0 = 0; k0 < GK; k0 += 64) {
#pragma unroll
    for (int r = 0; r < 4; ++r) {
      int c = tid + 256 * r;
      async_cp16(A2 + (size_t)(row0 + srow[r]) * GK + k0 + skc[r] * 8, As + c * 8);
      async_cp16(B2 + (size_t)(bcol0 + srow[r]) * GK + k0 + skc[r] * 8, Bs + c * 8);
    }
    __syncthreads();

#pragma unroll
    for (int kk2 = 0; kk2 < 2; ++kk2) {
      bf16x8_t af[4], bf[4];
#pragma unroll
      for (int i = 0; i < 4; ++i) {
        int row = wm + i * 16 + r15;
        int qc = (kk2 * 4 + quad) ^ (r15 & 7);
        af[i] = *(const bf16x8_t*)&As[row * 64 + qc * 8];
      }
#pragma unroll
      for (int j = 0; j < 4; ++j) {
        int row = wn + j * 16 + r15;
        int qc = (kk2 * 4 + quad) ^ (r15 & 7);
        bf[j] = *(const bf16x8_t*)&Bs[row * 64 + qc * 8];
      }
#pragma unroll
      for (int i = 0; i < 4; ++i)
#pragma unroll
        for (int j = 0; j < 4; ++j)
          acc[i][j] = __builtin_amdgcn_mfma_f32_16x16x32_bf16(af[i], bf[j], acc[i][j], 0, 0, 0);
    }
    __syncthreads();
  }

  // epilogue: C/D layout col=lane&15, row=(lane>>4)*4+reg; E = expf(dist)
  const float inv_nt = 1.f / 8192.f;
  float eev[4];
#pragma unroll
  for (int j = 0; j < 4; ++j) eev[j] = ee[ks + col0 + wn + j * 16 + r15];
#pragma unroll
  for (int i = 0; i < 4; ++i) {
#pragma unroll
    for (int r = 0; r < 4; ++r) {
      int grow = row0 + wm + i * 16 + quad * 4 + r;
      float xxv = xx[grow];
#pragma unroll
      for (int j = 0; j < 4; ++j) {
        int gcol = col0 + wn + j * 16 + r15;
        float dist = (xxv + eev[j] - 2.0f * acc[i][j][r]) * inv_nt;
        E[(size_t)grow * KC + gcol] = expf(dist);
      }
    }
  }
}

// ---------------- fp32 NT GEMM (fallback, r6-proven) with E-epilogue ----------------
__global__ __launch_bounds__(256) void gemm_nt_kernel(const float* __restrict__ A,
                                                      const float* __restrict__ B,
                                                      const float* __restrict__ xx,
                                                      const float* __restrict__ ee,
                                                      float* __restrict__ E,
                                                      int ks, int KC) {
  __shared__ __align__(16) float Asf[32][68];
  __shared__ __align__(16) float Bsf[32][68];
  int tid = threadIdx.x;
  int row0 = blockIdx.y * 64;
  int colB0 = blockIdx.x * 64 + ks;
  int tx = tid & 15, ty = tid >> 4;
  float acc[4][4] = {};
  for (int d0 = 0; d0 < N_DIM; d0 += 32) {
#pragma unroll
    for (int r = 0; r < 2; ++r) {
      int c = tid + 256 * r;
      int m = c >> 3;
      int dv = (c & 7) << 2;
      const float4 va = *(const float4*)(A + (size_t)(row0 + m) * N_DIM + d0 + dv);
      Asf[dv + 0][m] = va.x; Asf[dv + 1][m] = va.y;
      Asf[dv + 2][m] = va.z; Asf[dv + 3][m] = va.w;
      const float4 vb = *(const float4*)(B + (size_t)(colB0 + m) * N_DIM + d0 + dv);
      Bsf[dv + 0][m] = vb.x; Bsf[dv + 1][m] = vb.y;
      Bsf[dv + 2][m] = vb.z; Bsf[dv + 3][m] = vb.w;
    }
    __syncthreads();
#pragma unroll
    for (int dd = 0; dd < 32; ++dd) {
      float4 a4 = *(const float4*)&Asf[dd][ty << 2];
      float4 b4 = *(const float4*)&Bsf[dd][tx << 2];
      float av[4] = {a4.x, a4.y, a4.z, a4.w};
      float bv[4] = {b4.x, b4.y, b4.z, b4.w};
#pragma unroll
      for (int i = 0; i < 4; ++i)
#pragma unroll
        for (int j = 0; j < 4; ++j)
          acc[i][j] = fmaf(av[i], bv[j], acc[i][j]);
    }
    __syncthreads();
  }
  const float inv_nt = 1.f / 8192.f;
  int colC0 = blockIdx.x * 64;
  float eev[4];
#pragma unroll
  for (int j = 0; j < 4; ++j) eev[j] = ee[ks + colC0 + (tx << 2) + j];
#pragma unroll
  for (int i = 0; i < 4; ++i) {
    int grow = row0 + (ty << 2) + i;
    float xxv = xx[grow];
    float4 v;
    v.x = expf((xxv + eev[0] - 2.0f * acc[i][0]) * inv_nt);
    v.y = expf((xxv + eev[1] - 2.0f * acc[i][1]) * inv_nt);
    v.z = expf((xxv + eev[2] - 2.0f * acc[i][2]) * inv_nt);
    v.w = expf((xxv + eev[3] - 2.0f * acc[i][3]) * inv_nt);
    *(float4*)(E + (size_t)grow * KC + colC0 + (tx << 2)) = v;
  }
}

// ---------------- sampler: wave-shared champion + bits screen + E prefetch ----------------
__global__ __launch_bounds__(256) void sample_kernel(const float* __restrict__ E,
                                                     float* __restrict__ rmin,
                                                     int* __restrict__ ridx,
                                                     int ks, int KC,
                                                     uint32_t k0, uint32_t k1) {
  int lane = threadIdx.x & 63;
  int row = (int)((blockIdx.x * blockDim.x + threadIdx.x) >> 6);
  unsigned long long champ[N_SAMP];
  uint32_t th[N_SAMP];
#pragma unroll
  for (int s = 0; s < N_SAMP; ++s) { champ[s] = 0xFFFFFFFFFFFFFFFFULL; th[s] = 0u; }
  const float tiny = 1.1754943508222875e-38f;
  uint32_t row_c = (uint32_t)row * 81920u;
  const float* Erow = E + (size_t)row * KC;

  float Ek = Erow[lane];
  for (int kk = lane; kk < KC; kk += 64) {
    int nk = (kk + 64 < KC) ? kk + 64 : kk;
    float Ekn = Erow[nk];                     // prefetch next strip element
    uint32_t k = (uint32_t)(ks + kk);
    uint32_t base_c = row_c + k;
#pragma unroll
    for (int s = 0; s < N_SAMP; ++s) {
      uint32_t x0 = 0u, x1 = base_c + (uint32_t)s * 8192u;
      tf2x32(k0, k1, x0, x1);
      uint32_t bits = x0 ^ x1;
      bool cand = (bits >= th[s]);
      if (__any(cand)) {
        float u = __uint_as_float(0x3f800000u | (bits >> 9)) - 1.0f;
        u = fmaxf(u, tiny);
        float wv = -logf(u) * Ek;             // exact r6 arithmetic
        unsigned long long p = cand
            ? (((unsigned long long)__float_as_uint(wv) << 32) | k)
            : 0xFFFFFFFFFFFFFFFFULL;
#pragma unroll
        for (int off = 1; off < 64; off <<= 1) {
          unsigned long long op = shfl_xor_u64(p, off);
          p = (op < p) ? op : p;
        }
        if (p < champ[s]) {
          champ[s] = p;
          float wmin = __uint_as_float((uint32_t)(p >> 32));
          float ut = expf(-wmin) * 0.999999f;  // conservative; underflow->0 => no skip
          th[s] = ((uint32_t)(ut * 8388608.0f)) << 9;
        }
      }
    }
    Ek = Ekn;
  }
#pragma unroll
  for (int s = 0; s < N_SAMP; ++s) {
    if (lane == 0) {
      float v = __uint_as_float((uint32_t)(champ[s] >> 32));
      int id = (int)(uint32_t)(champ[s] & 0xFFFFFFFFu);
      size_t p = (size_t)row * N_SAMP + s;
      if (v < rmin[p]) { rmin[p] = v; ridx[p] = id; }
    }
  }
}

// ---------------- gather + mean + straight-through (float4) ----------------
__global__ __launch_bounds__(256) void gather_kernel(const float* __restrict__ emb,
                                                     const int* __restrict__ ridx,
                                                     const float* __restrict__ x,
                                                     float* __restrict__ outq,
                                                     float* __restrict__ outs) {
  int lane = threadIdx.x & 63;
  int row = (int)((blockIdx.x * blockDim.x + threadIdx.x) >> 6);
  int idx[N_SAMP];
#pragma unroll
  for (int s = 0; s < N_SAMP; ++s) idx[s] = ridx[row * N_SAMP + s];
  if (lane < N_SAMP) outs[row * N_SAMP + lane] = (float)idx[lane];
#pragma unroll
  for (int h = 0; h < 2; ++h) {
    int c = h * 256 + lane * 4;
    float4 sum = make_float4(0.f, 0.f, 0.f, 0.f);
#pragma unroll
    for (int s = 0; s < N_SAMP; ++s) {
      float4 e = *(const float4*)(emb + (size_t)idx[s] * N_DIM + c);
      sum.x += e.x; sum.y += e.y; sum.z += e.z; sum.w += e.w;
    }
    float4 xv = *(const float4*)(x + (size_t)row * N_DIM + c);
    float4 o;
    o.x = xv.x + (sum.x / 10.0f - xv.x);
    o.y = xv.y + (sum.y / 10.0f - xv.y);
    o.z = xv.z + (sum.z / 10.0f - xv.z);
    o.w = xv.w + (sum.w / 10.0f - xv.w);
    *(float4*)(outq + (size_t)row * N_DIM + c) = o;
  }
}

extern "C" void kernel_launch(void* const* d_in, const int* in_sizes, int n_in,
                              void* d_out, int out_size, void* d_ws, size_t ws_size,
                              hipStream_t stream) {
  const float* x = (const float*)d_in[0];
  const float* emb = (const float*)d_in[1];
  float* out_q = (float*)d_out;
  float* out_s = out_q + (size_t)N_ROWS * N_DIM;

  const size_t fixed_f = (size_t)N_ROWS + N_TOK + 2 * (size_t)N_ROWS * N_SAMP;  // 180224 floats
  const size_t out_f = (size_t)N_ROWS * N_DIM + (size_t)N_ROWS * N_SAMP;
  const size_t split_u = (size_t)N_ROWS * GK;

  uint32_t s0 = 0u, s1 = 1u;   // skey = fold_in(key(0), 1)
  tf2x32(0u, 0u, s0, s1);

  // ---- preferred path: bf16x2 MFMA GEMM, fixed + 2 splits + E strip in ws ----
  int KC = 0;
  for (int c = 8192; c >= 128; c >>= 1) {
    size_t need = fixed_f * 4 + 2 * split_u * 2 + (size_t)N_ROWS * c * 4;
    if (need <= ws_size) { KC = c; break; }
  }

  if (KC) {
    float* xx = (float*)d_ws;
    float* ee = xx + N_ROWS;
    float* rmin = ee + N_TOK;
    int* ridx = (int*)(rmin + (size_t)N_ROWS * N_SAMP);
    unsigned short* A2 = (unsigned short*)(ridx + (size_t)N_ROWS * N_SAMP);
    unsigned short* B2 = A2 + split_u;
    float* E = (float*)(B2 + split_u);

    rownorm_kernel<<<2048, 256, 0, stream>>>(x, xx);
    rownorm_kernel<<<2048, 256, 0, stream>>>(emb, ee);
    init_state_kernel<<<(N_ROWS * N_SAMP + 255) / 256, 256, 0, stream>>>(rmin, ridx);
    split_kernel<<<N_ROWS * 128 / 256, 256, 0, stream>>>(x, A2, 0);
    split_kernel<<<N_ROWS * 128 / 256, 256, 0, stream>>>(emb, B2, 1);

    for (int ks = 0; ks < N_TOK; ks += KC) {
      gemm_bf16_kernel<<<dim3(KC / 128, N_ROWS / 128), 256, 0, stream>>>(A2, B2, xx, ee, E, ks, KC);
      sample_kernel<<<2048, 256, 0, stream>>>(E, rmin, ridx, ks, KC, s0, s1);
    }
    gather_kernel<<<2048, 256, 0, stream>>>(emb, ridx, x, out_q, out_s);
    return;
  }

  // ---- fallback: fp32 path with adaptive placement ----
  float *xx, *ee, *rmin, *E;
  int* ridx;
  KC = 0;
  for (int c = 8192; c >= 64; c >>= 1) {
    if ((fixed_f + (size_t)N_ROWS * c) * 4 <= ws_size) { KC = c; break; }
  }
  if (KC) {
    xx = (float*)d_ws;
    ee = xx + N_ROWS;
    rmin = ee + N_TOK;
    ridx = (int*)(rmin + (size_t)N_ROWS * N_SAMP);
    E = (float*)(ridx + (size_t)N_ROWS * N_SAMP);
  } else if (fixed_f * 4 <= ws_size) {
    KC = 512;
    xx = (float*)d_ws;
    ee = xx + N_ROWS;
    rmin = ee + N_TOK;
    ridx = (int*)(rmin + (size_t)N_ROWS * N_SAMP);
    E = out_q;
  } else {
    KC = 256;
    E = out_q;
    float* tail = out_q + (out_f - fixed_f);
    xx = tail;
    ee = xx + N_ROWS;
    rmin = ee + N_TOK;
    ridx = (int*)(rmin + (size_t)N_ROWS * N_SAMP);
  }

  rownorm_kernel<<<2048, 256, 0, stream>>>(x, xx);
  rownorm_kernel<<<2048, 256, 0, stream>>>(emb, ee);
  init_state_kernel<<<(N_ROWS * N_SAMP + 255) / 256, 256, 0, stream>>>(rmin, ridx);
  for (int ks = 0; ks < N_TOK; ks += KC) {
    gemm_nt_kernel<<<dim3(KC / 64, N_ROWS / 64), 256, 0, stream>>>(x, emb, xx, ee, E, ks, KC);
    sample_kernel<<<2048, 256, 0, stream>>>(E, rmin, ridx, ks, KC, s0, s1);
  }
  gather_kernel<<<2048, 256, 0, stream>>>(emb, ridx, x, out_q, out_s);
}